// Round 1
// baseline (130.781 us; speedup 1.0000x reference)
//
#include <hip/hip_runtime.h>

// WMAE: out = sum_{i,j} w[j] * |t1[i,j] - t2[i,j]| / n_sample
// t1,t2: fp32 [4194304, 3] row-major. w = {300, 1, 200}.
// Memory-bound: ~100.7 MB read, one fp32 out. Target ~16 us @ 6.3 TB/s.

#define BLOCKS 2048
#define THREADS 256

__global__ void wmae_zero(float* out) {
    if (threadIdx.x == 0 && blockIdx.x == 0) out[0] = 0.0f;
}

__global__ __launch_bounds__(THREADS) void wmae_kernel(
    const float4* __restrict__ t1, const float4* __restrict__ t2,
    float* __restrict__ out, int nchunks, float inv_n) {
    float acc = 0.0f;
    const int stride = gridDim.x * blockDim.x;
    for (int i = blockIdx.x * blockDim.x + threadIdx.x; i < nchunks; i += stride) {
        float4 a = t1[i];
        float4 b = t2[i];
        // base element index = 4*i; 4 == 1 (mod 3) so base % 3 == i % 3.
        // elements base..base+3 have feature indices r, r+1, r+2, r (mod 3).
        int r = i % 3;
        // w[0]=300, w[1]=1, w[2]=200
        float w0 = (r == 0) ? 300.0f : ((r == 1) ? 1.0f : 200.0f);   // feature (r+0)%3
        float w1 = (r == 0) ? 1.0f   : ((r == 1) ? 200.0f : 300.0f); // feature (r+1)%3
        float w2 = (r == 0) ? 200.0f : ((r == 1) ? 300.0f : 1.0f);   // feature (r+2)%3
        acc += w0 * (fabsf(a.x - b.x) + fabsf(a.w - b.w))
             + w1 *  fabsf(a.y - b.y)
             + w2 *  fabsf(a.z - b.z);
    }
    // wave-64 shuffle reduction
    #pragma unroll
    for (int off = 32; off > 0; off >>= 1)
        acc += __shfl_down(acc, off, 64);
    __shared__ float smem[THREADS / 64];
    const int wave = threadIdx.x >> 6;
    const int lane = threadIdx.x & 63;
    if (lane == 0) smem[wave] = acc;
    __syncthreads();
    if (threadIdx.x == 0) {
        float t = smem[0] + smem[1] + smem[2] + smem[3];
        atomicAdd(out, t * inv_n);
    }
}

extern "C" void kernel_launch(void* const* d_in, const int* in_sizes, int n_in,
                              void* d_out, int out_size, void* d_ws, size_t ws_size,
                              hipStream_t stream) {
    const float4* t1 = (const float4*)d_in[0];
    const float4* t2 = (const float4*)d_in[1];
    float* out = (float*)d_out;

    const int n_elems = in_sizes[0];          // 4194304 * 3 = 12582912
    const int nchunks = n_elems / 4;          // divisible: 3145728
    const int n_sample = n_elems / 3;         // 4194304
    const float inv_n = 1.0f / (float)n_sample;

    wmae_zero<<<1, 64, 0, stream>>>(out);
    wmae_kernel<<<BLOCKS, THREADS, 0, stream>>>(t1, t2, out, nchunks, inv_n);
}

// Round 2
// 125.213 us; speedup vs baseline: 1.0445x; 1.0445x over previous
//
#include <hip/hip_runtime.h>

// WMAE: out = sum_{i,j} w[j] * |t1[i,j] - t2[i,j]| / n_sample
// t1,t2: fp32 [4194304, 3] row-major. w = {300, 1, 200}.
// Memory-bound reduction: ~100.7 MB read, one fp32 out.
// R1 was latency-bound (VGPR=12, rolled loop, 2 loads in flight).
// R2: block-tiled, 12 independent float4 loads per thread issued upfront.

#define THREADS 256
#define CPT 6                      // float4 chunks per thread
#define CHUNKS_PER_BLOCK (THREADS * CPT)   // 1536
#define BLOCKS 2048                // 2048 * 1536 = 3145728 chunks exactly

__global__ void wmae_zero(float* out) {
    if (threadIdx.x == 0 && blockIdx.x == 0) out[0] = 0.0f;
}

__device__ __forceinline__ float3 wsel(int r) {
    // weights for features (r, r+1, r+2) mod 3, where w = {300, 1, 200}
    float w0 = (r == 0) ? 300.0f : ((r == 1) ? 1.0f : 200.0f);
    float w1 = (r == 0) ? 1.0f   : ((r == 1) ? 200.0f : 300.0f);
    float w2 = (r == 0) ? 200.0f : ((r == 1) ? 300.0f : 1.0f);
    return make_float3(w0, w1, w2);
}

__global__ __launch_bounds__(THREADS) void wmae_kernel(
    const float4* __restrict__ t1, const float4* __restrict__ t2,
    float* __restrict__ out, float inv_n) {
    const int base = blockIdx.x * CHUNKS_PER_BLOCK + threadIdx.x;

    // Issue all 12 loads before any use: 192 B/thread in flight.
    float4 a[CPT], b[CPT];
    #pragma unroll
    for (int k = 0; k < CPT; ++k) a[k] = t1[base + k * THREADS];
    #pragma unroll
    for (int k = 0; k < CPT; ++k) b[k] = t2[base + k * THREADS];

    float acc = 0.0f;
    int r = base % 3;  // chunk index mod 3; chunk base elem = 4*i, 4 = 1 (mod 3)
    #pragma unroll
    for (int k = 0; k < CPT; ++k) {
        float3 w = wsel(r);
        acc += w.x * (fabsf(a[k].x - b[k].x) + fabsf(a[k].w - b[k].w))
             + w.y *  fabsf(a[k].y - b[k].y)
             + w.z *  fabsf(a[k].z - b[k].z);
        r = (r + 1) % 3;   // +256 chunks == +1 (mod 3); compile-time foldable
    }

    // wave-64 shuffle reduction
    #pragma unroll
    for (int off = 32; off > 0; off >>= 1)
        acc += __shfl_down(acc, off, 64);
    __shared__ float smem[THREADS / 64];
    const int wave = threadIdx.x >> 6;
    const int lane = threadIdx.x & 63;
    if (lane == 0) smem[wave] = acc;
    __syncthreads();
    if (threadIdx.x == 0) {
        float t = smem[0] + smem[1] + smem[2] + smem[3];
        atomicAdd(out, t * inv_n);
    }
}

extern "C" void kernel_launch(void* const* d_in, const int* in_sizes, int n_in,
                              void* d_out, int out_size, void* d_ws, size_t ws_size,
                              hipStream_t stream) {
    const float4* t1 = (const float4*)d_in[0];
    const float4* t2 = (const float4*)d_in[1];
    float* out = (float*)d_out;

    const int n_elems = in_sizes[0];          // 12582912
    const int n_sample = n_elems / 3;         // 4194304
    const float inv_n = 1.0f / (float)n_sample;

    wmae_zero<<<1, 64, 0, stream>>>(out);
    wmae_kernel<<<BLOCKS, THREADS, 0, stream>>>(t1, t2, out, inv_n);
}

// Round 3
// 113.527 us; speedup vs baseline: 1.1520x; 1.1029x over previous
//
#include <hip/hip_runtime.h>

// WMAE: out = sum_{i,j} w[j] * |t1[i,j] - t2[i,j]| / n_sample
// t1,t2: fp32 [4194304, 3] row-major. w = {300, 1, 200}.
// R2 post-mortem: ~36us kernel = 2.8 TB/s read; latency-hiding increase was
// neutral -> testing dispatch-balance theory (2 rounds/CU) + dropping the
// zero-kernel/atomic via two-phase partials in d_ws.

#define THREADS 256
#define CPT 3                                // float4 chunks per thread
#define CHUNKS_PER_BLOCK (THREADS * CPT)     // 768
#define P1_BLOCKS 4096                       // 4096 * 768 = 3145728 chunks exactly

__device__ __forceinline__ float3 wsel(int r) {
    // weights for features (r, r+1, r+2) mod 3, where w = {300, 1, 200}
    float w0 = (r == 0) ? 300.0f : ((r == 1) ? 1.0f : 200.0f);
    float w1 = (r == 0) ? 1.0f   : ((r == 1) ? 200.0f : 300.0f);
    float w2 = (r == 0) ? 200.0f : ((r == 1) ? 300.0f : 1.0f);
    return make_float3(w0, w1, w2);
}

__global__ __launch_bounds__(THREADS) void wmae_partial(
    const float4* __restrict__ t1, const float4* __restrict__ t2,
    float* __restrict__ partials, float inv_n) {
    const int base = blockIdx.x * CHUNKS_PER_BLOCK + threadIdx.x;

    float4 a[CPT], b[CPT];
    #pragma unroll
    for (int k = 0; k < CPT; ++k) a[k] = t1[base + k * THREADS];
    #pragma unroll
    for (int k = 0; k < CPT; ++k) b[k] = t2[base + k * THREADS];

    float acc = 0.0f;
    int r = base % 3;  // chunk base elem = 4*i, 4 == 1 (mod 3)
    #pragma unroll
    for (int k = 0; k < CPT; ++k) {
        float3 w = wsel(r);
        acc += w.x * (fabsf(a[k].x - b[k].x) + fabsf(a[k].w - b[k].w))
             + w.y *  fabsf(a[k].y - b[k].y)
             + w.z *  fabsf(a[k].z - b[k].z);
        r = (r + 1) % 3;   // +256 chunks == +1 (mod 3)
    }

    #pragma unroll
    for (int off = 32; off > 0; off >>= 1)
        acc += __shfl_down(acc, off, 64);
    __shared__ float smem[THREADS / 64];
    const int wave = threadIdx.x >> 6;
    const int lane = threadIdx.x & 63;
    if (lane == 0) smem[wave] = acc;
    __syncthreads();
    if (threadIdx.x == 0)
        partials[blockIdx.x] = (smem[0] + smem[1] + smem[2] + smem[3]) * inv_n;
}

__global__ __launch_bounds__(THREADS) void wmae_finish(
    const float* __restrict__ partials, float* __restrict__ out) {
    float acc = 0.0f;
    #pragma unroll
    for (int k = 0; k < P1_BLOCKS / THREADS; ++k)   // 16 strided, coalesced
        acc += partials[k * THREADS + threadIdx.x];
    #pragma unroll
    for (int off = 32; off > 0; off >>= 1)
        acc += __shfl_down(acc, off, 64);
    __shared__ float smem[THREADS / 64];
    const int wave = threadIdx.x >> 6;
    const int lane = threadIdx.x & 63;
    if (lane == 0) smem[wave] = acc;
    __syncthreads();
    if (threadIdx.x == 0)
        out[0] = smem[0] + smem[1] + smem[2] + smem[3];
}

extern "C" void kernel_launch(void* const* d_in, const int* in_sizes, int n_in,
                              void* d_out, int out_size, void* d_ws, size_t ws_size,
                              hipStream_t stream) {
    const float4* t1 = (const float4*)d_in[0];
    const float4* t2 = (const float4*)d_in[1];
    float* out = (float*)d_out;
    float* partials = (float*)d_ws;            // 4096 floats, overwritten fully

    const int n_elems = in_sizes[0];           // 12582912
    const int n_sample = n_elems / 3;          // 4194304
    const float inv_n = 1.0f / (float)n_sample;

    wmae_partial<<<P1_BLOCKS, THREADS, 0, stream>>>(t1, t2, partials, inv_n);
    wmae_finish<<<1, THREADS, 0, stream>>>(partials, out);
}

// Round 4
// 113.159 us; speedup vs baseline: 1.1557x; 1.0032x over previous
//
#include <hip/hip_runtime.h>

// WMAE: out = sum_{i,j} w[j] * |t1[i,j] - t2[i,j]| / n_sample
// t1,t2: fp32 [4194304, 3] row-major. w = {300, 1, 200}.
// R3 post-mortem: 2 rounds/CU -> partial ~24us (4.2 TB/s); ~86us of total is
// harness re-poison/restore (untouchable). R4: single fully-resident round:
// 4096 blocks x 128 thr (2 waves) = 16 blocks/CU = 32 waves/CU, CPT=6 ->
// whole CU assignment in flight, no round-2 stragglers.

#define THREADS 128
#define CPT 6                                // float4 chunks per thread
#define CHUNKS_PER_BLOCK (THREADS * CPT)     // 768
#define P1_BLOCKS 4096                       // 4096 * 768 = 3145728 chunks exactly

__device__ __forceinline__ float3 wsel(int r) {
    // weights for features (r, r+1, r+2) mod 3, where w = {300, 1, 200}
    float w0 = (r == 0) ? 300.0f : ((r == 1) ? 1.0f : 200.0f);
    float w1 = (r == 0) ? 1.0f   : ((r == 1) ? 200.0f : 300.0f);
    float w2 = (r == 0) ? 200.0f : ((r == 1) ? 300.0f : 1.0f);
    return make_float3(w0, w1, w2);
}

__global__ __launch_bounds__(THREADS, 8) void wmae_partial(
    const float4* __restrict__ t1, const float4* __restrict__ t2,
    float* __restrict__ partials, float inv_n) {
    const int base = blockIdx.x * CHUNKS_PER_BLOCK + threadIdx.x;

    // 12 independent 16B loads issued upfront: 192 B/lane in flight.
    float4 a[CPT], b[CPT];
    #pragma unroll
    for (int k = 0; k < CPT; ++k) a[k] = t1[base + k * THREADS];
    #pragma unroll
    for (int k = 0; k < CPT; ++k) b[k] = t2[base + k * THREADS];

    float acc = 0.0f;
    int r = base % 3;  // chunk base elem = 4*i, 4 == 1 (mod 3)
    #pragma unroll
    for (int k = 0; k < CPT; ++k) {
        float3 w = wsel(r);
        acc += w.x * (fabsf(a[k].x - b[k].x) + fabsf(a[k].w - b[k].w))
             + w.y *  fabsf(a[k].y - b[k].y)
             + w.z *  fabsf(a[k].z - b[k].z);
        r = (r + 2) % 3;   // +128 chunks == +2 (mod 3)
    }

    // wave-64 shuffle reduction (2 waves/block)
    #pragma unroll
    for (int off = 32; off > 0; off >>= 1)
        acc += __shfl_down(acc, off, 64);
    __shared__ float smem[THREADS / 64];
    const int wave = threadIdx.x >> 6;
    const int lane = threadIdx.x & 63;
    if (lane == 0) smem[wave] = acc;
    __syncthreads();
    if (threadIdx.x == 0)
        partials[blockIdx.x] = (smem[0] + smem[1]) * inv_n;
}

__global__ __launch_bounds__(256) void wmae_finish(
    const float* __restrict__ partials, float* __restrict__ out) {
    float acc = 0.0f;
    #pragma unroll
    for (int k = 0; k < P1_BLOCKS / 256; ++k)   // 16 strided, coalesced
        acc += partials[k * 256 + threadIdx.x];
    #pragma unroll
    for (int off = 32; off > 0; off >>= 1)
        acc += __shfl_down(acc, off, 64);
    __shared__ float smem[4];
    const int wave = threadIdx.x >> 6;
    const int lane = threadIdx.x & 63;
    if (lane == 0) smem[wave] = acc;
    __syncthreads();
    if (threadIdx.x == 0)
        out[0] = smem[0] + smem[1] + smem[2] + smem[3];
}

extern "C" void kernel_launch(void* const* d_in, const int* in_sizes, int n_in,
                              void* d_out, int out_size, void* d_ws, size_t ws_size,
                              hipStream_t stream) {
    const float4* t1 = (const float4*)d_in[0];
    const float4* t2 = (const float4*)d_in[1];
    float* out = (float*)d_out;
    float* partials = (float*)d_ws;            // 4096 floats, fully overwritten

    const int n_elems = in_sizes[0];           // 12582912
    const int n_sample = n_elems / 3;          // 4194304
    const float inv_n = 1.0f / (float)n_sample;

    wmae_partial<<<P1_BLOCKS, THREADS, 0, stream>>>(t1, t2, partials, inv_n);
    wmae_finish<<<1, 256, 0, stream>>>(partials, out);
}